// Round 6
// baseline (121.209 us; speedup 1.0000x reference)
//
#include <hip/hip_runtime.h>
#include <hip/hip_bf16.h>
#include <stdint.h>

#define B_   4
#define C_   256
#define CQK_ 32
#define N_   4096

typedef float f32x4  __attribute__((ext_vector_type(4)));
typedef short bf16x8 __attribute__((ext_vector_type(8)));
typedef unsigned uint4v __attribute__((ext_vector_type(4)));

__device__ __forceinline__ unsigned short f2bf(float f) {
    unsigned u = __builtin_bit_cast(unsigned, f);
    u += 0x7FFFu + ((u >> 16) & 1u);   // RNE
    return (unsigned short)(u >> 16);
}
__device__ __forceinline__ unsigned pack2(float a, float b) {
    return (unsigned)f2bf(a) | ((unsigned)f2bf(b) << 16);
}

// V fragment layout, with the swapped-QK k-slot permutation baked in:
// within a 64-m tile: h=(m>>5)&1 selects the wave m-half; within the half,
// MFMA k-index kappa = lg*8 + j maps to m5 = ((j>>2))*16 + lg*4 + (j&3).
// elem (b,e,m) at [b][m>>6][h][e>>4][ ((m>>2)&3)*16 + (e&15) ][ ((m>>4)&1)*4 + (m&3) ]
__device__ __forceinline__ size_t vfrag_off(int b, int e, int m) {
    const int kt = m >> 6, h = (m >> 5) & 1;
    const int j  = ((m >> 4) & 1) * 4 + (m & 3);
    const int lgp = (m >> 2) & 3;
    return (((((size_t)b * 64 + kt) * 2 + h) * 16 + (e >> 4)) * 64
            + (size_t)lgp * 16 + (e & 15)) * 8 + j;
}

// ---------------- pass 1: fp32 [b][c][n] -> bf16 [b][n][c] (+ W -> bf16) ----------------
__global__ __launch_bounds__(256) void transpose_kernel(
        const float* __restrict__ x, const float* __restrict__ y,
        const float* __restrict__ Wq, const float* __restrict__ Wk,
        const float* __restrict__ Wv,
        unsigned short* __restrict__ xb, unsigned short* __restrict__ yb,
        unsigned short* __restrict__ Wqb, unsigned short* __restrict__ Wkb,
        unsigned short* __restrict__ Wvb) {
    const int bid = blockIdx.x, tid = threadIdx.x;
    if (bid < 512) {
        __shared__ char lds[64 * 528];          // 64 pixel-rows x 256 bf16 (+16B pad)
        const bool isx = bid < 256;
        const int slab = bid & 255;
        const int b  = slab >> 6;
        const int n0 = (slab & 63) * 64;
        const float* __restrict__ src = isx ? x : y;
        unsigned short* __restrict__ dst = isx ? xb : yb;
        const int l = tid & 63, wv = tid >> 6;
        const float* sp = src + (size_t)(b * C_) * N_ + n0 + l;
#pragma unroll
        for (int i = 0; i < 64; i += 2) {
            const int c = wv * 64 + i;
            const float v0 = sp[(size_t)c * N_];
            const float v1 = sp[(size_t)(c + 1) * N_];
            *(unsigned*)(lds + l * 528 + c * 2) = pack2(v0, v1);
        }
        __syncthreads();
        const int n = tid >> 5, chunk = tid & 31;
#pragma unroll
        for (int j = 0; j < 8; ++j) {
            const int nn = n + j * 8;
            const uint4v v = *(const uint4v*)(lds + nn * 528 + chunk * 16);
            *(uint4v*)((char*)(dst + ((size_t)b * N_ + n0 + nn) * C_) + chunk * 16) = v;
        }
    } else {
        for (int p = (bid - 512) * 256 + tid; p < 40960; p += 64 * 256) {
            const float* s; unsigned short* d; int off;
            if (p < 4096)      { s = Wq; d = Wqb; off = p; }
            else if (p < 8192) { s = Wk; d = Wkb; off = p - 4096; }
            else               { s = Wv; d = Wvb; off = p - 8192; }
            *(unsigned*)(d + off * 2) = pack2(s[off * 2], s[off * 2 + 1]);
        }
    }
}

// ---------------- pass 2: MFMA projections, no LDS ----------------
__global__ __launch_bounds__(256) void proj_gemm(
        const unsigned short* __restrict__ xb, const unsigned short* __restrict__ yb,
        const unsigned short* __restrict__ Wqb, const unsigned short* __restrict__ Wkb,
        const unsigned short* __restrict__ Wvb,
        const float* __restrict__ bq, const float* __restrict__ bk,
        const float* __restrict__ bv,
        unsigned short* __restrict__ qf, unsigned short* __restrict__ kf,
        unsigned short* __restrict__ vf) {
    const int tid = threadIdx.x, w = tid >> 6, l = tid & 63;
    const int lr = l & 15, lg = l >> 4;
    const int gid = blockIdx.x;
    const int b  = (gid >> 1) & 3;
    const int n0 = ((((gid >> 3) << 1) | (gid & 1))) * 64;

    f32x4 accV[4][4];    // [eblk][mblk]
    f32x4 accQ[4];
#pragma unroll
    for (int e = 0; e < 4; ++e)
#pragma unroll
        for (int m = 0; m < 4; ++m) accV[e][m] = (f32x4){0.f, 0.f, 0.f, 0.f};
#pragma unroll
    for (int m = 0; m < 4; ++m) accQ[m] = (f32x4){0.f, 0.f, 0.f, 0.f};

    const unsigned short* __restrict__ Wqk = (w < 2) ? Wqb : Wkb;
    const int d0 = (w & 1) * 16;

#pragma unroll
    for (int ks = 0; ks < 8; ++ks) {
        const int c0 = ks * 32 + lg * 8;
        bf16x8 aY[4], aS[4];
#pragma unroll
        for (int mb = 0; mb < 4; ++mb)
            aY[mb] = *(const bf16x8*)(yb + ((size_t)b * N_ + n0 + mb * 16 + lr) * C_ + c0);
        if (w < 2) {
#pragma unroll
            for (int mb = 0; mb < 4; ++mb)
                aS[mb] = *(const bf16x8*)(xb + ((size_t)b * N_ + n0 + mb * 16 + lr) * C_ + c0);
        } else {
#pragma unroll
            for (int mb = 0; mb < 4; ++mb) aS[mb] = aY[mb];
        }
        bf16x8 bV[4];
#pragma unroll
        for (int eb = 0; eb < 4; ++eb)
            bV[eb] = *(const bf16x8*)(Wvb + (size_t)(w * 64 + eb * 16 + lr) * C_ + c0);
        const bf16x8 bQ = *(const bf16x8*)(Wqk + (size_t)(d0 + lr) * C_ + c0);
#pragma unroll
        for (int eb = 0; eb < 4; ++eb)
#pragma unroll
            for (int mb = 0; mb < 4; ++mb)
                accV[eb][mb] = __builtin_amdgcn_mfma_f32_16x16x32_bf16(
                    aY[mb], bV[eb], accV[eb][mb], 0, 0, 0);
#pragma unroll
        for (int mb = 0; mb < 4; ++mb)
            accQ[mb] = __builtin_amdgcn_mfma_f32_16x16x32_bf16(aS[mb], bQ, accQ[mb], 0, 0, 0);
    }

    // V epilogue: rows m = n0+mb*16+lg*4+r (r -> consecutive j), col e -> 8B stores
#pragma unroll
    for (int eb = 0; eb < 4; ++eb) {
        const int e = w * 64 + eb * 16 + lr;
        const float bve = bv[e];
#pragma unroll
        for (int mb = 0; mb < 4; ++mb) {
            const size_t off = vfrag_off(b, e, n0 + mb * 16 + lg * 4);
            unsigned* p = (unsigned*)(vf + off);
            p[0] = pack2(accV[eb][mb][0] + bve, accV[eb][mb][1] + bve);
            p[1] = pack2(accV[eb][mb][2] + bve, accV[eb][mb][3] + bve);
        }
    }
    const float bqv = ((w < 2) ? bq : bk)[d0 + lr];
    unsigned short* __restrict__ dqk = (w < 2) ? qf : kf;
#pragma unroll
    for (int mb = 0; mb < 4; ++mb)
#pragma unroll
        for (int r = 0; r < 4; ++r) {
            const int n = n0 + mb * 16 + lg * 4 + r;
            dqk[((size_t)b * N_ + n) * CQK_ + d0 + lr] = f2bf(accQ[mb][r] + bqv);
        }
}

// ---------------- fused flash attention, swapped-QK in-register P ----------------
// 4 waves: qb=w&1 (16 q-rows), mh=w>>1 (32-m half). No LDS/barriers in main loop.
__global__ __launch_bounds__(256) void attn_kernel(
        const unsigned short* __restrict__ qf, const unsigned short* __restrict__ kf,
        const unsigned short* __restrict__ vf, const float* __restrict__ x,
        const float* __restrict__ gamma, float* __restrict__ out) {
    __shared__ f32x4 cO[2][2][8][64];   // [qb][half][ebi][lane]
    __shared__ float cL[2][2][16];
    const int tid = threadIdx.x, w = tid >> 6, l = tid & 63;
    const int lr = l & 15, lg = l >> 4;
    const int gid = blockIdx.x;
    const int b  = (gid >> 1) & 3;
    const int q0 = (((gid >> 3) << 1) | (gid & 1)) * 32;
    const int qb = w & 1, mh = w >> 1, oh = 1 - mh;

    const bf16x8 qfrag = *(const bf16x8*)(
        qf + ((size_t)b * N_ + q0 + qb * 16 + lr) * CQK_ + lg * 8);

    f32x4 acc[16];
#pragma unroll
    for (int i = 0; i < 16; ++i) acc[i] = (f32x4){0.f, 0.f, 0.f, 0.f};
    float Lp = 0.f;

    const unsigned short* kbase = kf + ((size_t)b * N_ + mh * 32 + lr) * CQK_ + lg * 8;
    const unsigned short* vbase = vf + (size_t)(b * 128 + mh) * 8192 + l * 8;

    for (int kt = 0; kt < N_ / 64; ++kt) {
        const unsigned short* kp = kbase + (size_t)kt * 64 * CQK_;
        const bf16x8 kfa0 = *(const bf16x8*)(kp);
        const bf16x8 kfa1 = *(const bf16x8*)(kp + 16 * CQK_);
        const unsigned short* vp = vbase + (size_t)kt * 16384;
        bf16x8 vb[16];
#pragma unroll
        for (int eb = 0; eb < 8; ++eb) vb[eb] = *(const bf16x8*)(vp + eb * 512);

        // swapped QK^T: D[m][q], col=lane&15=q, row=lg*4+r=m5 within i*16 block
        const f32x4 ea0 = __builtin_amdgcn_mfma_f32_16x16x32_bf16(
            kfa0, qfrag, (f32x4){0.f, 0.f, 0.f, 0.f}, 0, 0, 0);
        const f32x4 ea1 = __builtin_amdgcn_mfma_f32_16x16x32_bf16(
            kfa1, qfrag, (f32x4){0.f, 0.f, 0.f, 0.f}, 0, 0, 0);

#pragma unroll
        for (int eb = 8; eb < 16; ++eb) vb[eb] = *(const bf16x8*)(vp + eb * 512);

        float p0[4], p1[4];
#pragma unroll
        for (int r = 0; r < 4; ++r) { p0[r] = __expf(ea0[r]); p1[r] = __expf(ea1[r]); }
#pragma unroll
        for (int r = 0; r < 4; ++r) Lp += p0[r] + p1[r];

        // pack P into the PV A-fragment: j = i*4+r  (v_cvt_pk: S0->lo, S1->hi)
        uint4v pu;
        asm("v_cvt_pk_bf16_f32 %0, %1, %2" : "=v"(pu[0]) : "v"(p0[0]), "v"(p0[1]));
        asm("v_cvt_pk_bf16_f32 %0, %1, %2" : "=v"(pu[1]) : "v"(p0[2]), "v"(p0[3]));
        asm("v_cvt_pk_bf16_f32 %0, %1, %2" : "=v"(pu[2]) : "v"(p1[0]), "v"(p1[1]));
        asm("v_cvt_pk_bf16_f32 %0, %1, %2" : "=v"(pu[3]) : "v"(p1[2]), "v"(p1[3]));
        const bf16x8 pa = __builtin_bit_cast(bf16x8, pu);

#pragma unroll
        for (int eb = 0; eb < 16; ++eb)
            acc[eb] = __builtin_amdgcn_mfma_f32_16x16x32_bf16(pa, vb[eb], acc[eb], 0, 0, 0);
    }

    // L over lg-groups (lanes sharing l&15)
    Lp += __shfl_xor(Lp, 16);
    Lp += __shfl_xor(Lp, 32);

    // exchange: each wave gives away its OTHER e-half, keeps its own (eblk in [mh*8, mh*8+8))
#pragma unroll
    for (int ebi = 0; ebi < 8; ++ebi) cO[qb][oh][ebi][l] = acc[oh * 8 + ebi];
    if (l < 16) cL[qb][mh][l] = Lp;
    __syncthreads();

    const float Ltot = Lp + cL[qb][oh][lr];
    float rI[4];
#pragma unroll
    for (int r = 0; r < 4; ++r) rI[r] = 1.0f / __shfl(Ltot, lg * 4 + r);

    const float g = gamma[0];
    const int nb = q0 + qb * 16 + lg * 4;
#pragma unroll
    for (int ebi = 0; ebi < 8; ++ebi) {
        const int eblk = mh * 8 + ebi;
        const int e = eblk * 16 + lr;
        const f32x4 part = cO[qb][mh][ebi][l];
        const size_t idx = ((size_t)b * C_ + e) * N_ + nb;
        const f32x4 xv = *(const f32x4*)(x + idx);
        f32x4 ov;
#pragma unroll
        for (int r = 0; r < 4; ++r)
            ov[r] = g * (acc[eblk][r] + part[r]) * rI[r] + xv[r];
        *(f32x4*)(out + idx) = ov;
    }
}

extern "C" void kernel_launch(void* const* d_in, const int* in_sizes, int n_in,
                              void* d_out, int out_size, void* d_ws, size_t ws_size,
                              hipStream_t stream) {
    (void)in_sizes; (void)n_in; (void)out_size; (void)ws_size;
    const float* x     = (const float*)d_in[0];
    const float* y     = (const float*)d_in[1];
    const float* Wq    = (const float*)d_in[2];
    const float* bq    = (const float*)d_in[3];
    const float* Wk    = (const float*)d_in[4];
    const float* bk    = (const float*)d_in[5];
    const float* Wv    = (const float*)d_in[6];
    const float* bv    = (const float*)d_in[7];
    const float* gamma = (const float*)d_in[8];
    float* out = (float*)d_out;

    unsigned short* qf  = (unsigned short*)d_ws;
    unsigned short* kf  = qf + (size_t)B_ * N_ * CQK_;
    unsigned short* vf  = kf + (size_t)B_ * N_ * CQK_;
    unsigned short* Wqb = vf + (size_t)B_ * N_ * C_;
    unsigned short* Wkb = Wqb + CQK_ * C_;
    unsigned short* Wvb = Wkb + CQK_ * C_;

    unsigned short* xb = (unsigned short*)d_out;   // dead until attn epilogue
    unsigned short* yb = xb + (size_t)B_ * N_ * C_;

    transpose_kernel<<<dim3(576), 256, 0, stream>>>(x, y, Wq, Wk, Wv, xb, yb, Wqb, Wkb, Wvb);
    proj_gemm<<<dim3(256), 256, 0, stream>>>(xb, yb, Wqb, Wkb, Wvb, bq, bk, bv, qf, kf, vf);
    attn_kernel<<<dim3(512), 256, 0, stream>>>(qf, kf, vf, x, gamma, out);
}

// Round 7
// 82.072 us; speedup vs baseline: 1.4769x; 1.4769x over previous
//
#include <hip/hip_runtime.h>
#include <hip/hip_bf16.h>
#include <stdint.h>

#define B_   4
#define C_   256
#define CQK_ 32
#define N_   4096

typedef float f32x4  __attribute__((ext_vector_type(4)));
typedef short bf16x8 __attribute__((ext_vector_type(8)));
typedef unsigned uint4v __attribute__((ext_vector_type(4)));

__device__ __forceinline__ unsigned short f2bf(float f) {
    unsigned u = __builtin_bit_cast(unsigned, f);
    u += 0x7FFFu + ((u >> 16) & 1u);   // RNE
    return (unsigned short)(u >> 16);
}
__device__ __forceinline__ unsigned pack2(float a, float b) {
    return (unsigned)f2bf(a) | ((unsigned)f2bf(b) << 16);
}

// V fragment layout (plain m-order): B-frag of PV mfma is lane-linear.
// elem (b,e,m) -> [b][m>>5][e>>4][ ((m>>3)&3)*16 + (e&15) ][ m&7 ]
__device__ __forceinline__ size_t vfrag_off(int b, int e, int m) {
    return ((((size_t)b * 128 + (m >> 5)) * 16 + (e >> 4)) * 64
            + (size_t)((m >> 3) & 3) * 16 + (e & 15)) * 8 + (m & 7);
}

// ---------------- pass 1: fp32 [b][c][n] -> bf16 [b][n][c] (+ W -> bf16) ----------------
__global__ __launch_bounds__(256) void transpose_kernel(
        const float* __restrict__ x, const float* __restrict__ y,
        const float* __restrict__ Wq, const float* __restrict__ Wk,
        const float* __restrict__ Wv,
        unsigned short* __restrict__ xb, unsigned short* __restrict__ yb,
        unsigned short* __restrict__ Wqb, unsigned short* __restrict__ Wkb,
        unsigned short* __restrict__ Wvb) {
    const int bid = blockIdx.x, tid = threadIdx.x;
    if (bid < 512) {
        __shared__ char lds[64 * 528];          // 64 pixel-rows x 256 bf16 (+16B pad)
        const bool isx = bid < 256;
        const int slab = bid & 255;
        const int b  = slab >> 6;
        const int n0 = (slab & 63) * 64;
        const float* __restrict__ src = isx ? x : y;
        unsigned short* __restrict__ dst = isx ? xb : yb;
        const int l = tid & 63, wv = tid >> 6;
        const float* sp = src + (size_t)(b * C_) * N_ + n0 + l;
#pragma unroll
        for (int i = 0; i < 64; i += 2) {
            const int c = wv * 64 + i;
            const float v0 = sp[(size_t)c * N_];
            const float v1 = sp[(size_t)(c + 1) * N_];
            *(unsigned*)(lds + l * 528 + c * 2) = pack2(v0, v1);
        }
        __syncthreads();
        const int n = tid >> 5, chunk = tid & 31;
#pragma unroll
        for (int j = 0; j < 8; ++j) {
            const int nn = n + j * 8;
            const uint4v v = *(const uint4v*)(lds + nn * 528 + chunk * 16);
            *(uint4v*)((char*)(dst + ((size_t)b * N_ + n0 + nn) * C_) + chunk * 16) = v;
        }
    } else {
        for (int p = (bid - 512) * 256 + tid; p < 40960; p += 64 * 256) {
            const float* s; unsigned short* d; int off;
            if (p < 4096)      { s = Wq; d = Wqb; off = p; }
            else if (p < 8192) { s = Wk; d = Wkb; off = p - 4096; }
            else               { s = Wv; d = Wvb; off = p - 8192; }
            *(unsigned*)(d + off * 2) = pack2(s[off * 2], s[off * 2 + 1]);
        }
    }
}

// ---------------- pass 2: MFMA projections, no LDS ----------------
__global__ __launch_bounds__(256) void proj_gemm(
        const unsigned short* __restrict__ xb, const unsigned short* __restrict__ yb,
        const unsigned short* __restrict__ Wqb, const unsigned short* __restrict__ Wkb,
        const unsigned short* __restrict__ Wvb,
        const float* __restrict__ bq, const float* __restrict__ bk,
        const float* __restrict__ bv,
        unsigned short* __restrict__ qf, unsigned short* __restrict__ kf,
        unsigned short* __restrict__ vf) {
    const int tid = threadIdx.x, w = tid >> 6, l = tid & 63;
    const int lr = l & 15, lg = l >> 4;
    const int gid = blockIdx.x;
    const int b  = (gid >> 1) & 3;
    const int n0 = ((((gid >> 3) << 1) | (gid & 1))) * 64;

    f32x4 accV[4][4];    // [eblk][mblk]
    f32x4 accQ[4];
#pragma unroll
    for (int e = 0; e < 4; ++e)
#pragma unroll
        for (int m = 0; m < 4; ++m) accV[e][m] = (f32x4){0.f, 0.f, 0.f, 0.f};
#pragma unroll
    for (int m = 0; m < 4; ++m) accQ[m] = (f32x4){0.f, 0.f, 0.f, 0.f};

    const unsigned short* __restrict__ Wqk = (w < 2) ? Wqb : Wkb;
    const int d0 = (w & 1) * 16;

#pragma unroll
    for (int ks = 0; ks < 8; ++ks) {
        const int c0 = ks * 32 + lg * 8;
        bf16x8 aY[4], aS[4];
#pragma unroll
        for (int mb = 0; mb < 4; ++mb)
            aY[mb] = *(const bf16x8*)(yb + ((size_t)b * N_ + n0 + mb * 16 + lr) * C_ + c0);
        if (w < 2) {
#pragma unroll
            for (int mb = 0; mb < 4; ++mb)
                aS[mb] = *(const bf16x8*)(xb + ((size_t)b * N_ + n0 + mb * 16 + lr) * C_ + c0);
        } else {
#pragma unroll
            for (int mb = 0; mb < 4; ++mb) aS[mb] = aY[mb];
        }
        bf16x8 bV[4];
#pragma unroll
        for (int eb = 0; eb < 4; ++eb)
            bV[eb] = *(const bf16x8*)(Wvb + (size_t)(w * 64 + eb * 16 + lr) * C_ + c0);
        const bf16x8 bQ = *(const bf16x8*)(Wqk + (size_t)(d0 + lr) * C_ + c0);
#pragma unroll
        for (int eb = 0; eb < 4; ++eb)
#pragma unroll
            for (int mb = 0; mb < 4; ++mb)
                accV[eb][mb] = __builtin_amdgcn_mfma_f32_16x16x32_bf16(
                    aY[mb], bV[eb], accV[eb][mb], 0, 0, 0);
#pragma unroll
        for (int mb = 0; mb < 4; ++mb)
            accQ[mb] = __builtin_amdgcn_mfma_f32_16x16x32_bf16(aS[mb], bQ, accQ[mb], 0, 0, 0);
    }

    // V epilogue: rows m = n0+mb*16+lg*4+r (4 consecutive m -> 8B store)
#pragma unroll
    for (int eb = 0; eb < 4; ++eb) {
        const int e = w * 64 + eb * 16 + lr;
        const float bve = bv[e];
#pragma unroll
        for (int mb = 0; mb < 4; ++mb) {
            const size_t off = vfrag_off(b, e, n0 + mb * 16 + lg * 4);
            unsigned* p = (unsigned*)(vf + off);
            p[0] = pack2(accV[eb][mb][0] + bve, accV[eb][mb][1] + bve);
            p[1] = pack2(accV[eb][mb][2] + bve, accV[eb][mb][3] + bve);
        }
    }
    const float bqv = ((w < 2) ? bq : bk)[d0 + lr];
    unsigned short* __restrict__ dqk = (w < 2) ? qf : kf;
#pragma unroll
    for (int mb = 0; mb < 4; ++mb)
#pragma unroll
        for (int r = 0; r < 4; ++r) {
            const int n = n0 + mb * 16 + lg * 4 + r;
            dqk[((size_t)b * N_ + n) * CQK_ + d0 + lr] = f2bf(accQ[mb][r] + bqv);
        }
}

// ---------------- fused flash attention: TQ=64, TK=128, 8 waves, e-split PV ----------------
// Wave w: QK for m-block w (16 m) x all 64 q; PV for e-range w*32 (no V duplication).
// P exchanged via double-buffered XOR-swizzled LDS. V/K prefetched after the barrier.
__global__ __launch_bounds__(512, 2) void attn_kernel(
        const unsigned short* __restrict__ qf, const unsigned short* __restrict__ kf,
        const unsigned short* __restrict__ vf, const float* __restrict__ x,
        const float* __restrict__ gamma, float* __restrict__ out) {
    __shared__ char plds[2][16384];     // P: [64q][128m] bf16, 16B-slot XOR swizzle
    __shared__ float cLs[8][64];
    __shared__ float cLt[64];
    const int tid = threadIdx.x, w = tid >> 6, l = tid & 63;
    const int lr = l & 15, lg = l >> 4;
    const int gid = blockIdx.x;
    const int b  = (gid >> 1) & 3;                       // batch -> XCD pair
    const int q0 = ((((gid >> 3) << 1) | (gid & 1))) * 64;

    // loop-invariant Q fragments (B-operand of swapped QK^T)
    bf16x8 qfr[4];
#pragma unroll
    for (int qblk = 0; qblk < 4; ++qblk)
        qfr[qblk] = *(const bf16x8*)(
            qf + ((size_t)b * N_ + q0 + qblk * 16 + lr) * CQK_ + lg * 8);

    f32x4 acc[4][2];                    // [qblk][ebi] ; e = (w*2+ebi)*16 + lr
#pragma unroll
    for (int i = 0; i < 4; ++i) { acc[i][0] = (f32x4){0,0,0,0}; acc[i][1] = (f32x4){0,0,0,0}; }
    float Lacc[4] = {0.f, 0.f, 0.f, 0.f};

    const unsigned short* kbase = kf + ((size_t)b * N_ + w * 16 + lr) * CQK_ + lg * 8;

    // prologue loads (tile 0)
    bf16x8 kfr = *(const bf16x8*)(kbase);
    bf16x8 vb[2][4];
#pragma unroll
    for (int ks = 0; ks < 4; ++ks)
#pragma unroll
        for (int ebi = 0; ebi < 2; ++ebi)
            vb[ebi][ks] = *(const bf16x8*)(
                vf + ((((size_t)(b * 128 + ks)) * 16 + w * 2 + ebi) * 64 + l) * 8);

    for (int kt = 0; kt < 32; ++kt) {
        // QK^T (swapped): D[m16][q16]; lane holds q=qblk*16+lr, m=w*16+lg*4+r
        f32x4 e4[4];
#pragma unroll
        for (int qblk = 0; qblk < 4; ++qblk)
            e4[qblk] = __builtin_amdgcn_mfma_f32_16x16x32_bf16(
                kfr, qfr[qblk], (f32x4){0.f, 0.f, 0.f, 0.f}, 0, 0, 0);

        // exp + pack + swizzled LDS write (energies O(1): no max subtraction)
        char* pw = plds[kt & 1];
        const int m2 = w * 16 + lg * 4;
#pragma unroll
        for (int qblk = 0; qblk < 4; ++qblk) {
            const float p0 = __expf(e4[qblk][0]);
            const float p1 = __expf(e4[qblk][1]);
            const float p2 = __expf(e4[qblk][2]);
            const float p3 = __expf(e4[qblk][3]);
            Lacc[qblk] += (p0 + p1) + (p2 + p3);
            unsigned u0, u1;
            asm("v_cvt_pk_bf16_f32 %0, %1, %2" : "=v"(u0) : "v"(p0), "v"(p1));
            asm("v_cvt_pk_bf16_f32 %0, %1, %2" : "=v"(u1) : "v"(p2), "v"(p3));
            const int q = qblk * 16 + lr;
            const int byte = q * 256 + (((m2 >> 3) ^ (q & 7)) << 4) + (m2 & 7) * 2;
            *(unsigned long long*)(pw + byte) =
                (unsigned long long)u0 | ((unsigned long long)u1 << 32);
        }
        __syncthreads();

        // prefetch tile kt+1 AFTER the barrier: latency hides under PV's MFMAs
        const int ktn = (kt + 1) & 31;          // wrap: last-iter loads are dead but valid
        const bf16x8 kfr_n = *(const bf16x8*)(kbase + (size_t)ktn * 128 * CQK_);
        bf16x8 vbn[2][4];
#pragma unroll
        for (int ks = 0; ks < 4; ++ks)
#pragma unroll
            for (int ebi = 0; ebi < 2; ++ebi)
                vbn[ebi][ks] = *(const bf16x8*)(
                    vf + ((((size_t)(b * 128 + ktn * 4 + ks)) * 16 + w * 2 + ebi) * 64 + l) * 8);

        // PV: acc[q][e] += P[q][m-chunk] * V[m-chunk][e]
#pragma unroll
        for (int ks = 0; ks < 4; ++ks)
#pragma unroll
            for (int qblk = 0; qblk < 4; ++qblk) {
                const int q = qblk * 16 + lr;
                const bf16x8 pa = *(const bf16x8*)(
                    pw + q * 256 + (((ks * 4 + lg) ^ (q & 7)) << 4));
                acc[qblk][0] = __builtin_amdgcn_mfma_f32_16x16x32_bf16(
                    pa, vb[0][ks], acc[qblk][0], 0, 0, 0);
                acc[qblk][1] = __builtin_amdgcn_mfma_f32_16x16x32_bf16(
                    pa, vb[1][ks], acc[qblk][1], 0, 0, 0);
            }

        kfr = kfr_n;
#pragma unroll
        for (int ks = 0; ks < 4; ++ks) { vb[0][ks] = vbn[0][ks]; vb[1][ks] = vbn[1][ks]; }
    }

    // L: reduce over lg-groups, then across the 8 waves (each owns a disjoint m-block set)
#pragma unroll
    for (int qblk = 0; qblk < 4; ++qblk) {
        Lacc[qblk] += __shfl_xor(Lacc[qblk], 16);
        Lacc[qblk] += __shfl_xor(Lacc[qblk], 32);
    }
    if (l < 16) {
#pragma unroll
        for (int qblk = 0; qblk < 4; ++qblk) cLs[w][qblk * 16 + lr] = Lacc[qblk];
    }
    __syncthreads();
    if (tid < 64) {
        float s = 0.f;
#pragma unroll
        for (int w2 = 0; w2 < 8; ++w2) s += cLs[w2][tid];
        cLt[tid] = 1.0f / s;
    }
    __syncthreads();

    const float g = gamma[0];
#pragma unroll
    for (int qblk = 0; qblk < 4; ++qblk) {
        float rI[4];
#pragma unroll
        for (int r = 0; r < 4; ++r) rI[r] = cLt[qblk * 16 + lg * 4 + r];
        const int nb = q0 + qblk * 16 + lg * 4;
#pragma unroll
        for (int ebi = 0; ebi < 2; ++ebi) {
            const int e = (w * 2 + ebi) * 16 + lr;
            const size_t idx = ((size_t)b * C_ + e) * N_ + nb;
            const f32x4 xv = *(const f32x4*)(x + idx);
            f32x4 ov;
#pragma unroll
            for (int r = 0; r < 4; ++r)
                ov[r] = g * acc[qblk][ebi][r] * rI[r] + xv[r];
            *(f32x4*)(out + idx) = ov;
        }
    }
}

extern "C" void kernel_launch(void* const* d_in, const int* in_sizes, int n_in,
                              void* d_out, int out_size, void* d_ws, size_t ws_size,
                              hipStream_t stream) {
    (void)in_sizes; (void)n_in; (void)out_size; (void)ws_size;
    const float* x     = (const float*)d_in[0];
    const float* y     = (const float*)d_in[1];
    const float* Wq    = (const float*)d_in[2];
    const float* bq    = (const float*)d_in[3];
    const float* Wk    = (const float*)d_in[4];
    const float* bk    = (const float*)d_in[5];
    const float* Wv    = (const float*)d_in[6];
    const float* bv    = (const float*)d_in[7];
    const float* gamma = (const float*)d_in[8];
    float* out = (float*)d_out;

    unsigned short* qf  = (unsigned short*)d_ws;
    unsigned short* kf  = qf + (size_t)B_ * N_ * CQK_;
    unsigned short* vf  = kf + (size_t)B_ * N_ * CQK_;
    unsigned short* Wqb = vf + (size_t)B_ * N_ * C_;
    unsigned short* Wkb = Wqb + CQK_ * C_;
    unsigned short* Wvb = Wkb + CQK_ * C_;

    unsigned short* xb = (unsigned short*)d_out;   // dead until attn epilogue
    unsigned short* yb = xb + (size_t)B_ * N_ * C_;

    transpose_kernel<<<dim3(576), 256, 0, stream>>>(x, y, Wq, Wk, Wv, xb, yb, Wqb, Wkb, Wvb);
    proj_gemm<<<dim3(256), 256, 0, stream>>>(xb, yb, Wqb, Wkb, Wvb, bq, bk, bv, qf, kf, vf);
    attn_kernel<<<dim3(256), 512, 0, stream>>>(qf, kf, vf, x, gamma, out);
}

// Round 9
// 81.478 us; speedup vs baseline: 1.4876x; 1.0073x over previous
//
#include <hip/hip_runtime.h>
#include <hip/hip_bf16.h>
#include <stdint.h>

#define B_   4
#define C_   256
#define CQK_ 32
#define N_   4096

typedef float f32x4  __attribute__((ext_vector_type(4)));
typedef short bf16x8 __attribute__((ext_vector_type(8)));
typedef unsigned uint4v __attribute__((ext_vector_type(4)));

__device__ __forceinline__ unsigned short f2bf(float f) {
    unsigned u = __builtin_bit_cast(unsigned, f);
    u += 0x7FFFu + ((u >> 16) & 1u);   // RNE
    return (unsigned short)(u >> 16);
}
__device__ __forceinline__ unsigned pack2(float a, float b) {
    return (unsigned)f2bf(a) | ((unsigned)f2bf(b) << 16);
}

// V fragment layout (plain m-order, round-7 verified): PV B-frag is lane-linear.
// elem (b,e,m) -> [b][m>>5][e>>4][ ((m>>3)&3)*16 + (e&15) ][ m&7 ]
__device__ __forceinline__ size_t vfrag_off(int b, int e, int m) {
    return ((((size_t)b * 128 + (m >> 5)) * 16 + (e >> 4)) * 64
            + (size_t)((m >> 3) & 3) * 16 + (e & 15)) * 8 + (m & 7);
}

// ---------------- pass 1: fp32 [b][c][n] -> bf16 [b][n][c] (+ W -> bf16) ----------------
__global__ __launch_bounds__(256) void transpose_kernel(
        const float* __restrict__ x, const float* __restrict__ y,
        const float* __restrict__ Wq, const float* __restrict__ Wk,
        const float* __restrict__ Wv,
        unsigned short* __restrict__ xb, unsigned short* __restrict__ yb,
        unsigned short* __restrict__ Wqb, unsigned short* __restrict__ Wkb,
        unsigned short* __restrict__ Wvb) {
    const int bid = blockIdx.x, tid = threadIdx.x;
    if (bid < 512) {
        __shared__ char lds[64 * 528];          // 64 pixel-rows x 256 bf16 (+16B pad)
        const bool isx = bid < 256;
        const int slab = bid & 255;
        const int b  = slab >> 6;
        const int n0 = (slab & 63) * 64;
        const float* __restrict__ src = isx ? x : y;
        unsigned short* __restrict__ dst = isx ? xb : yb;
        const int l = tid & 63, wv = tid >> 6;
        const float* sp = src + (size_t)(b * C_) * N_ + n0 + l;
#pragma unroll
        for (int i = 0; i < 64; i += 2) {
            const int c = wv * 64 + i;
            const float v0 = sp[(size_t)c * N_];
            const float v1 = sp[(size_t)(c + 1) * N_];
            *(unsigned*)(lds + l * 528 + c * 2) = pack2(v0, v1);
        }
        __syncthreads();
        const int n = tid >> 5, chunk = tid & 31;
#pragma unroll
        for (int j = 0; j < 8; ++j) {
            const int nn = n + j * 8;
            const uint4v v = *(const uint4v*)(lds + nn * 528 + chunk * 16);
            *(uint4v*)((char*)(dst + ((size_t)b * N_ + n0 + nn) * C_) + chunk * 16) = v;
        }
    } else {
        for (int p = (bid - 512) * 256 + tid; p < 40960; p += 64 * 256) {
            const float* s; unsigned short* d; int off;
            if (p < 4096)      { s = Wq; d = Wqb; off = p; }
            else if (p < 8192) { s = Wk; d = Wkb; off = p - 4096; }
            else               { s = Wv; d = Wvb; off = p - 8192; }
            *(unsigned*)(d + off * 2) = pack2(s[off * 2], s[off * 2 + 1]);
        }
    }
}

// ---------------- pass 2: MFMA projections, no LDS (round-7 verified) ----------------
__global__ __launch_bounds__(256) void proj_gemm(
        const unsigned short* __restrict__ xb, const unsigned short* __restrict__ yb,
        const unsigned short* __restrict__ Wqb, const unsigned short* __restrict__ Wkb,
        const unsigned short* __restrict__ Wvb,
        const float* __restrict__ bq, const float* __restrict__ bk,
        const float* __restrict__ bv,
        unsigned short* __restrict__ qf, unsigned short* __restrict__ kf,
        unsigned short* __restrict__ vf) {
    const int tid = threadIdx.x, w = tid >> 6, l = tid & 63;
    const int lr = l & 15, lg = l >> 4;
    const int gid = blockIdx.x;
    const int b  = (gid >> 1) & 3;
    const int n0 = ((((gid >> 3) << 1) | (gid & 1))) * 64;

    f32x4 accV[4][4];    // [eblk][mblk]
    f32x4 accQ[4];
#pragma unroll
    for (int e = 0; e < 4; ++e)
#pragma unroll
        for (int m = 0; m < 4; ++m) accV[e][m] = (f32x4){0.f, 0.f, 0.f, 0.f};
#pragma unroll
    for (int m = 0; m < 4; ++m) accQ[m] = (f32x4){0.f, 0.f, 0.f, 0.f};

    const unsigned short* __restrict__ Wqk = (w < 2) ? Wqb : Wkb;
    const int d0 = (w & 1) * 16;

#pragma unroll
    for (int ks = 0; ks < 8; ++ks) {
        const int c0 = ks * 32 + lg * 8;
        bf16x8 aY[4], aS[4];
#pragma unroll
        for (int mb = 0; mb < 4; ++mb)
            aY[mb] = *(const bf16x8*)(yb + ((size_t)b * N_ + n0 + mb * 16 + lr) * C_ + c0);
        if (w < 2) {
#pragma unroll
            for (int mb = 0; mb < 4; ++mb)
                aS[mb] = *(const bf16x8*)(xb + ((size_t)b * N_ + n0 + mb * 16 + lr) * C_ + c0);
        } else {
#pragma unroll
            for (int mb = 0; mb < 4; ++mb) aS[mb] = aY[mb];
        }
        bf16x8 bV[4];
#pragma unroll
        for (int eb = 0; eb < 4; ++eb)
            bV[eb] = *(const bf16x8*)(Wvb + (size_t)(w * 64 + eb * 16 + lr) * C_ + c0);
        const bf16x8 bQ = *(const bf16x8*)(Wqk + (size_t)(d0 + lr) * C_ + c0);
#pragma unroll
        for (int eb = 0; eb < 4; ++eb)
#pragma unroll
            for (int mb = 0; mb < 4; ++mb)
                accV[eb][mb] = __builtin_amdgcn_mfma_f32_16x16x32_bf16(
                    aY[mb], bV[eb], accV[eb][mb], 0, 0, 0);
#pragma unroll
        for (int mb = 0; mb < 4; ++mb)
            accQ[mb] = __builtin_amdgcn_mfma_f32_16x16x32_bf16(aS[mb], bQ, accQ[mb], 0, 0, 0);
    }

    // V epilogue: rows m = n0+mb*16+lg*4+r (4 consecutive m -> 8B store)
#pragma unroll
    for (int eb = 0; eb < 4; ++eb) {
        const int e = w * 64 + eb * 16 + lr;
        const float bve = bv[e];
#pragma unroll
        for (int mb = 0; mb < 4; ++mb) {
            const size_t off = vfrag_off(b, e, n0 + mb * 16 + lg * 4);
            unsigned* p = (unsigned*)(vf + off);
            p[0] = pack2(accV[eb][mb][0] + bve, accV[eb][mb][1] + bve);
            p[1] = pack2(accV[eb][mb][2] + bve, accV[eb][mb][3] + bve);
        }
    }
    const float bqv = ((w < 2) ? bq : bk)[d0 + lr];
    unsigned short* __restrict__ dqk = (w < 2) ? qf : kf;
#pragma unroll
    for (int mb = 0; mb < 4; ++mb)
#pragma unroll
        for (int r = 0; r < 4; ++r) {
            const int n = n0 + mb * 16 + lg * 4 + r;
            dqk[((size_t)b * N_ + n) * CQK_ + d0 + lr] = f2bf(accQ[mb][r] + bqv);
        }
}

// ---------------- fused flash attention: TQ=64, TK=128, 8 waves, e-split PV ----------------
// Round-7 structure (verified). Edits: (1) P rows stride 272 B -> bank-rotated,
// conflict-free, no XOR; (2) write-side lgkmcnt(0)+raw s_barrier (vmcnt NOT drained)
// with K/V prefetch issued before the barrier so it flies across it.
__global__ __launch_bounds__(512, 2) void attn_kernel(
        const unsigned short* __restrict__ qf, const unsigned short* __restrict__ kf,
        const unsigned short* __restrict__ vf, const float* __restrict__ x,
        const float* __restrict__ gamma, float* __restrict__ out) {
    __shared__ char plds[2][64 * 272];  // P: [64q][128m] bf16, 272B row stride
    __shared__ float cLs[8][64];
    __shared__ float cLt[64];
    const int tid = threadIdx.x, w = tid >> 6, l = tid & 63;
    const int lr = l & 15, lg = l >> 4;
    const int gid = blockIdx.x;
    const int b  = (gid >> 1) & 3;                       // batch -> XCD pair
    const int q0 = ((((gid >> 3) << 1) | (gid & 1))) * 64;

    // loop-invariant Q fragments (B-operand of swapped QK^T)
    bf16x8 qfr[4];
#pragma unroll
    for (int qblk = 0; qblk < 4; ++qblk)
        qfr[qblk] = *(const bf16x8*)(
            qf + ((size_t)b * N_ + q0 + qblk * 16 + lr) * CQK_ + lg * 8);

    f32x4 acc[4][2];                    // [qblk][ebi] ; e = (w*2+ebi)*16 + lr
#pragma unroll
    for (int i = 0; i < 4; ++i) { acc[i][0] = (f32x4){0,0,0,0}; acc[i][1] = (f32x4){0,0,0,0}; }
    float Lacc[4] = {0.f, 0.f, 0.f, 0.f};

    const unsigned short* kbase = kf + ((size_t)b * N_ + w * 16 + lr) * CQK_ + lg * 8;

    // prologue loads (tile 0)
    bf16x8 kfr = *(const bf16x8*)(kbase);
    bf16x8 vb[2][4];
#pragma unroll
    for (int ks = 0; ks < 4; ++ks)
#pragma unroll
        for (int ebi = 0; ebi < 2; ++ebi)
            vb[ebi][ks] = *(const bf16x8*)(
                vf + ((((size_t)(b * 128 + ks)) * 16 + w * 2 + ebi) * 64 + l) * 8);

    for (int kt = 0; kt < 32; ++kt) {
        // QK^T (swapped): D[m16][q16]; lane holds q=qblk*16+lr, m=w*16+lg*4+r
        f32x4 e4[4];
#pragma unroll
        for (int qblk = 0; qblk < 4; ++qblk)
            e4[qblk] = __builtin_amdgcn_mfma_f32_16x16x32_bf16(
                kfr, qfr[qblk], (f32x4){0.f, 0.f, 0.f, 0.f}, 0, 0, 0);

        // issue next tile's K/V prefetch NOW: stays in flight across the raw barrier
        const int ktn = (kt + 1) & 31;          // wrap: last-iter loads are dead but valid
        const bf16x8 kfr_n = *(const bf16x8*)(kbase + (size_t)ktn * 128 * CQK_);
        bf16x8 vbn[2][4];
#pragma unroll
        for (int ks = 0; ks < 4; ++ks)
#pragma unroll
            for (int ebi = 0; ebi < 2; ++ebi)
                vbn[ebi][ks] = *(const bf16x8*)(
                    vf + ((((size_t)(b * 128 + ktn * 4 + ks)) * 16 + w * 2 + ebi) * 64 + l) * 8);

        // exp + pack + P-write (stride-272 rows: bank-group rotates with q)
        char* pw = plds[kt & 1];
        const int m2 = w * 16 + lg * 4;
#pragma unroll
        for (int qblk = 0; qblk < 4; ++qblk) {
            const float p0 = __expf(e4[qblk][0]);
            const float p1 = __expf(e4[qblk][1]);
            const float p2 = __expf(e4[qblk][2]);
            const float p3 = __expf(e4[qblk][3]);
            Lacc[qblk] += (p0 + p1) + (p2 + p3);
            unsigned u0, u1;
            asm("v_cvt_pk_bf16_f32 %0, %1, %2" : "=v"(u0) : "v"(p0), "v"(p1));
            asm("v_cvt_pk_bf16_f32 %0, %1, %2" : "=v"(u1) : "v"(p2), "v"(p3));
            const int q = qblk * 16 + lr;
            const int byte = q * 272 + ((m2 >> 3) << 4) + (m2 & 7) * 2;
            *(unsigned long long*)(pw + byte) =
                (unsigned long long)u0 | ((unsigned long long)u1 << 32);
        }

        // write-visibility protocol: retire LDS writes, raw barrier (no vmcnt drain)
        asm volatile("s_waitcnt lgkmcnt(0)" ::: "memory");
        __builtin_amdgcn_s_barrier();
        asm volatile("" ::: "memory");

        // PV: acc[q][e] += P[q][m-chunk] * V[m-chunk][e]
#pragma unroll
        for (int ks = 0; ks < 4; ++ks)
#pragma unroll
            for (int qblk = 0; qblk < 4; ++qblk) {
                const int q = qblk * 16 + lr;
                const bf16x8 pa = *(const bf16x8*)(
                    pw + q * 272 + ((ks * 4 + lg) << 4));
                acc[qblk][0] = __builtin_amdgcn_mfma_f32_16x16x32_bf16(
                    pa, vb[0][ks], acc[qblk][0], 0, 0, 0);
                acc[qblk][1] = __builtin_amdgcn_mfma_f32_16x16x32_bf16(
                    pa, vb[1][ks], acc[qblk][1], 0, 0, 0);
            }

        kfr = kfr_n;
#pragma unroll
        for (int ks = 0; ks < 4; ++ks) { vb[0][ks] = vbn[0][ks]; vb[1][ks] = vbn[1][ks]; }
    }

    // L: reduce over lg-groups, then across the 8 waves (disjoint m-block sets)
#pragma unroll
    for (int qblk = 0; qblk < 4; ++qblk) {
        Lacc[qblk] += __shfl_xor(Lacc[qblk], 16);
        Lacc[qblk] += __shfl_xor(Lacc[qblk], 32);
    }
    if (l < 16) {
#pragma unroll
        for (int qblk = 0; qblk < 4; ++qblk) cLs[w][qblk * 16 + lr] = Lacc[qblk];
    }
    __syncthreads();
    if (tid < 64) {
        float s = 0.f;
#pragma unroll
        for (int w2 = 0; w2 < 8; ++w2) s += cLs[w2][tid];
        cLt[tid] = 1.0f / s;
    }
    __syncthreads();

    const float g = gamma[0];
#pragma unroll
    for (int qblk = 0; qblk < 4; ++qblk) {
        float rI[4];
#pragma unroll
        for (int r = 0; r < 4; ++r) rI[r] = cLt[qblk * 16 + lg * 4 + r];
        const int nb = q0 + qblk * 16 + lg * 4;
#pragma unroll
        for (int ebi = 0; ebi < 2; ++ebi) {
            const int e = (w * 2 + ebi) * 16 + lr;
            const size_t idx = ((size_t)b * C_ + e) * N_ + nb;
            const f32x4 xv = *(const f32x4*)(x + idx);
            f32x4 ov;
#pragma unroll
            for (int r = 0; r < 4; ++r)
                ov[r] = g * acc[qblk][ebi][r] * rI[r] + xv[r];
            *(f32x4*)(out + idx) = ov;
        }
    }
}

extern "C" void kernel_launch(void* const* d_in, const int* in_sizes, int n_in,
                              void* d_out, int out_size, void* d_ws, size_t ws_size,
                              hipStream_t stream) {
    (void)in_sizes; (void)n_in; (void)out_size; (void)ws_size;
    const float* x     = (const float*)d_in[0];
    const float* y     = (const float*)d_in[1];
    const float* Wq    = (const float*)d_in[2];
    const float* bq    = (const float*)d_in[3];
    const float* Wk    = (const float*)d_in[4];
    const float* bk    = (const float*)d_in[5];
    const float* Wv    = (const float*)d_in[6];
    const float* bv    = (const float*)d_in[7];
    const float* gamma = (const float*)d_in[8];
    float* out = (float*)d_out;

    unsigned short* qf  = (unsigned short*)d_ws;
    unsigned short* kf  = qf + (size_t)B_ * N_ * CQK_;
    unsigned short* vf  = kf + (size_t)B_ * N_ * CQK_;
    unsigned short* Wqb = vf + (size_t)B_ * N_ * C_;
    unsigned short* Wkb = Wqb + CQK_ * C_;
    unsigned short* Wvb = Wkb + CQK_ * C_;

    unsigned short* xb = (unsigned short*)d_out;   // dead until attn epilogue
    unsigned short* yb = xb + (size_t)B_ * N_ * C_;

    transpose_kernel<<<dim3(576), 256, 0, stream>>>(x, y, Wq, Wk, Wv, xb, yb, Wqb, Wkb, Wvb);
    proj_gemm<<<dim3(256), 256, 0, stream>>>(xb, yb, Wqb, Wkb, Wvb, bq, bk, bv, qf, kf, vf);
    attn_kernel<<<dim3(256), 512, 0, stream>>>(qf, kf, vf, x, gamma, out);
}

// Round 10
// 77.369 us; speedup vs baseline: 1.5666x; 1.0531x over previous
//
#include <hip/hip_runtime.h>
#include <hip/hip_bf16.h>
#include <stdint.h>

#define B_   4
#define C_   256
#define CQK_ 32
#define N_   4096

typedef float f32x4  __attribute__((ext_vector_type(4)));
typedef short bf16x8 __attribute__((ext_vector_type(8)));
typedef unsigned uint4v __attribute__((ext_vector_type(4)));

__device__ __forceinline__ unsigned short f2bf(float f) {
    unsigned u = __builtin_bit_cast(unsigned, f);
    u += 0x7FFFu + ((u >> 16) & 1u);   // RNE
    return (unsigned short)(u >> 16);
}
__device__ __forceinline__ unsigned pack2(float a, float b) {
    return (unsigned)f2bf(a) | ((unsigned)f2bf(b) << 16);
}

// V fragment layout (plain m-order, round-7/9 verified): PV B-frag is lane-linear.
// elem (b,e,m) -> [b][m>>5][e>>4][ ((m>>3)&3)*16 + (e&15) ][ m&7 ]
__device__ __forceinline__ size_t vfrag_off(int b, int e, int m) {
    return ((((size_t)b * 128 + (m >> 5)) * 16 + (e >> 4)) * 64
            + (size_t)((m >> 3) & 3) * 16 + (e & 15)) * 8 + (m & 7);
}

// ---------------- pass 1: fp32 [b][c][n] -> bf16 [b][n][c] (+ W -> bf16) ----------------
__global__ __launch_bounds__(256) void transpose_kernel(
        const float* __restrict__ x, const float* __restrict__ y,
        const float* __restrict__ Wq, const float* __restrict__ Wk,
        const float* __restrict__ Wv,
        unsigned short* __restrict__ xb, unsigned short* __restrict__ yb,
        unsigned short* __restrict__ Wqb, unsigned short* __restrict__ Wkb,
        unsigned short* __restrict__ Wvb) {
    const int bid = blockIdx.x, tid = threadIdx.x;
    if (bid < 512) {
        __shared__ char lds[64 * 528];          // 64 pixel-rows x 256 bf16 (+16B pad)
        const bool isx = bid < 256;
        const int slab = bid & 255;
        const int b  = slab >> 6;
        const int n0 = (slab & 63) * 64;
        const float* __restrict__ src = isx ? x : y;
        unsigned short* __restrict__ dst = isx ? xb : yb;
        const int l = tid & 63, wv = tid >> 6;
        const float* sp = src + (size_t)(b * C_) * N_ + n0 + l;
#pragma unroll
        for (int i = 0; i < 64; i += 2) {
            const int c = wv * 64 + i;
            const float v0 = sp[(size_t)c * N_];
            const float v1 = sp[(size_t)(c + 1) * N_];
            *(unsigned*)(lds + l * 528 + c * 2) = pack2(v0, v1);
        }
        __syncthreads();
        const int n = tid >> 5, chunk = tid & 31;
#pragma unroll
        for (int j = 0; j < 8; ++j) {
            const int nn = n + j * 8;
            const uint4v v = *(const uint4v*)(lds + nn * 528 + chunk * 16);
            *(uint4v*)((char*)(dst + ((size_t)b * N_ + n0 + nn) * C_) + chunk * 16) = v;
        }
    } else {
        for (int p = (bid - 512) * 256 + tid; p < 40960; p += 64 * 256) {
            const float* s; unsigned short* d; int off;
            if (p < 4096)      { s = Wq; d = Wqb; off = p; }
            else if (p < 8192) { s = Wk; d = Wkb; off = p - 4096; }
            else               { s = Wv; d = Wvb; off = p - 8192; }
            *(unsigned*)(d + off * 2) = pack2(s[off * 2], s[off * 2 + 1]);
        }
    }
}

// ---------------- pass 2: MFMA projections, no LDS (round-7/9 verified) ----------------
__global__ __launch_bounds__(256) void proj_gemm(
        const unsigned short* __restrict__ xb, const unsigned short* __restrict__ yb,
        const unsigned short* __restrict__ Wqb, const unsigned short* __restrict__ Wkb,
        const unsigned short* __restrict__ Wvb,
        const float* __restrict__ bq, const float* __restrict__ bk,
        const float* __restrict__ bv,
        unsigned short* __restrict__ qf, unsigned short* __restrict__ kf,
        unsigned short* __restrict__ vf) {
    const int tid = threadIdx.x, w = tid >> 6, l = tid & 63;
    const int lr = l & 15, lg = l >> 4;
    const int gid = blockIdx.x;
    const int b  = (gid >> 1) & 3;
    const int n0 = ((((gid >> 3) << 1) | (gid & 1))) * 64;

    f32x4 accV[4][4];    // [eblk][mblk]
    f32x4 accQ[4];
#pragma unroll
    for (int e = 0; e < 4; ++e)
#pragma unroll
        for (int m = 0; m < 4; ++m) accV[e][m] = (f32x4){0.f, 0.f, 0.f, 0.f};
#pragma unroll
    for (int m = 0; m < 4; ++m) accQ[m] = (f32x4){0.f, 0.f, 0.f, 0.f};

    const unsigned short* __restrict__ Wqk = (w < 2) ? Wqb : Wkb;
    const int d0 = (w & 1) * 16;

#pragma unroll
    for (int ks = 0; ks < 8; ++ks) {
        const int c0 = ks * 32 + lg * 8;
        bf16x8 aY[4], aS[4];
#pragma unroll
        for (int mb = 0; mb < 4; ++mb)
            aY[mb] = *(const bf16x8*)(yb + ((size_t)b * N_ + n0 + mb * 16 + lr) * C_ + c0);
        if (w < 2) {
#pragma unroll
            for (int mb = 0; mb < 4; ++mb)
                aS[mb] = *(const bf16x8*)(xb + ((size_t)b * N_ + n0 + mb * 16 + lr) * C_ + c0);
        } else {
#pragma unroll
            for (int mb = 0; mb < 4; ++mb) aS[mb] = aY[mb];
        }
        bf16x8 bV[4];
#pragma unroll
        for (int eb = 0; eb < 4; ++eb)
            bV[eb] = *(const bf16x8*)(Wvb + (size_t)(w * 64 + eb * 16 + lr) * C_ + c0);
        const bf16x8 bQ = *(const bf16x8*)(Wqk + (size_t)(d0 + lr) * C_ + c0);
#pragma unroll
        for (int eb = 0; eb < 4; ++eb)
#pragma unroll
            for (int mb = 0; mb < 4; ++mb)
                accV[eb][mb] = __builtin_amdgcn_mfma_f32_16x16x32_bf16(
                    aY[mb], bV[eb], accV[eb][mb], 0, 0, 0);
#pragma unroll
        for (int mb = 0; mb < 4; ++mb)
            accQ[mb] = __builtin_amdgcn_mfma_f32_16x16x32_bf16(aS[mb], bQ, accQ[mb], 0, 0, 0);
    }

    // V epilogue: rows m = n0+mb*16+lg*4+r (4 consecutive m -> 8B store)
#pragma unroll
    for (int eb = 0; eb < 4; ++eb) {
        const int e = w * 64 + eb * 16 + lr;
        const float bve = bv[e];
#pragma unroll
        for (int mb = 0; mb < 4; ++mb) {
            const size_t off = vfrag_off(b, e, n0 + mb * 16 + lg * 4);
            unsigned* p = (unsigned*)(vf + off);
            p[0] = pack2(accV[eb][mb][0] + bve, accV[eb][mb][1] + bve);
            p[1] = pack2(accV[eb][mb][2] + bve, accV[eb][mb][3] + bve);
        }
    }
    const float bqv = ((w < 2) ? bq : bk)[d0 + lr];
    unsigned short* __restrict__ dqk = (w < 2) ? qf : kf;
#pragma unroll
    for (int mb = 0; mb < 4; ++mb)
#pragma unroll
        for (int r = 0; r < 4; ++r) {
            const int n = n0 + mb * 16 + lg * 4 + r;
            dqk[((size_t)b * N_ + n) * CQK_ + d0 + lr] = f2bf(accQ[mb][r] + bqv);
        }
}

// ---------------- fused flash attention: TQ=64, TK=128, 8 waves, e-split PV ----------------
// Round-9 structure; NEW: 2-deep ping-pong register pipeline (no reg copies ->
// no forced vmcnt drain per tile; compiler emits counted waits at first use)
// + s_setprio(1) around the PV MFMA cluster (T5).
__global__ __launch_bounds__(512, 2) void attn_kernel(
        const unsigned short* __restrict__ qf, const unsigned short* __restrict__ kf,
        const unsigned short* __restrict__ vf, const float* __restrict__ x,
        const float* __restrict__ gamma, float* __restrict__ out) {
    __shared__ char plds[2][64 * 272];  // P: [64q][128m] bf16, 272B row stride
    __shared__ float cLs[8][64];
    __shared__ float cLt[64];
    const int tid = threadIdx.x, w = tid >> 6, l = tid & 63;
    const int lr = l & 15, lg = l >> 4;
    const int gid = blockIdx.x;
    const int b  = (gid >> 1) & 3;                       // batch -> XCD pair
    const int q0 = ((((gid >> 3) << 1) | (gid & 1))) * 64;

    // loop-invariant Q fragments (B-operand of swapped QK^T)
    bf16x8 qfr[4];
#pragma unroll
    for (int qblk = 0; qblk < 4; ++qblk)
        qfr[qblk] = *(const bf16x8*)(
            qf + ((size_t)b * N_ + q0 + qblk * 16 + lr) * CQK_ + lg * 8);

    f32x4 acc[4][2];                    // [qblk][ebi] ; e = (w*2+ebi)*16 + lr
#pragma unroll
    for (int i = 0; i < 4; ++i) { acc[i][0] = (f32x4){0,0,0,0}; acc[i][1] = (f32x4){0,0,0,0}; }
    float Lacc[4] = {0.f, 0.f, 0.f, 0.f};

    const unsigned short* kbase = kf + ((size_t)b * N_ + w * 16 + lr) * CQK_ + lg * 8;

#define PREFETCH(KT, KFR, VB)                                                  \
    {                                                                          \
        const int t_ = (KT) & 31;                                              \
        KFR = *(const bf16x8*)(kbase + (size_t)t_ * 128 * CQK_);               \
        _Pragma("unroll")                                                      \
        for (int ks_ = 0; ks_ < 4; ++ks_)                                      \
            _Pragma("unroll")                                                  \
            for (int ebi_ = 0; ebi_ < 2; ++ebi_)                               \
                VB[ebi_][ks_] = *(const bf16x8*)(                              \
                    vf + ((((size_t)(b * 128 + t_ * 4 + ks_)) * 16             \
                           + w * 2 + ebi_) * 64 + l) * 8);                     \
    }

#define TILE_BODY(PW, KFR, VB)                                                 \
    {                                                                          \
        f32x4 e4_[4];                                                          \
        _Pragma("unroll")                                                      \
        for (int qblk = 0; qblk < 4; ++qblk)                                   \
            e4_[qblk] = __builtin_amdgcn_mfma_f32_16x16x32_bf16(               \
                KFR, qfr[qblk], (f32x4){0.f, 0.f, 0.f, 0.f}, 0, 0, 0);         \
        const int m2_ = w * 16 + lg * 4;                                       \
        _Pragma("unroll")                                                      \
        for (int qblk = 0; qblk < 4; ++qblk) {                                 \
            const float p0 = __expf(e4_[qblk][0]);                             \
            const float p1 = __expf(e4_[qblk][1]);                             \
            const float p2 = __expf(e4_[qblk][2]);                             \
            const float p3 = __expf(e4_[qblk][3]);                             \
            Lacc[qblk] += (p0 + p1) + (p2 + p3);                               \
            unsigned u0, u1;                                                   \
            asm("v_cvt_pk_bf16_f32 %0, %1, %2" : "=v"(u0) : "v"(p0), "v"(p1)); \
            asm("v_cvt_pk_bf16_f32 %0, %1, %2" : "=v"(u1) : "v"(p2), "v"(p3)); \
            const int q_ = qblk * 16 + lr;                                     \
            const int byte_ = q_ * 272 + ((m2_ >> 3) << 4) + (m2_ & 7) * 2;    \
            *(unsigned long long*)((PW) + byte_) =                             \
                (unsigned long long)u0 | ((unsigned long long)u1 << 32);       \
        }                                                                      \
        asm volatile("s_waitcnt lgkmcnt(0)" ::: "memory");                     \
        __builtin_amdgcn_s_barrier();                                          \
        asm volatile("" ::: "memory");                                         \
        __builtin_amdgcn_s_setprio(1);                                         \
        _Pragma("unroll")                                                      \
        for (int ks_ = 0; ks_ < 4; ++ks_)                                      \
            _Pragma("unroll")                                                  \
            for (int qblk = 0; qblk < 4; ++qblk) {                             \
                const int q_ = qblk * 16 + lr;                                 \
                const bf16x8 pa_ = *(const bf16x8*)(                           \
                    (PW) + q_ * 272 + ((ks_ * 4 + lg) << 4));                  \
                acc[qblk][0] = __builtin_amdgcn_mfma_f32_16x16x32_bf16(        \
                    pa_, VB[0][ks_], acc[qblk][0], 0, 0, 0);                   \
                acc[qblk][1] = __builtin_amdgcn_mfma_f32_16x16x32_bf16(        \
                    pa_, VB[1][ks_], acc[qblk][1], 0, 0, 0);                   \
            }                                                                  \
        __builtin_amdgcn_s_setprio(0);                                         \
    }

    bf16x8 kA, kB;
    bf16x8 vA[2][4], vB[2][4];
    PREFETCH(0, kA, vA);
    PREFETCH(1, kB, vB);

    for (int kt = 0; kt < 32; kt += 2) {
        TILE_BODY(plds[0], kA, vA);
        PREFETCH(kt + 2, kA, vA);       // issued early; consumed next even tile
        TILE_BODY(plds[1], kB, vB);
        PREFETCH(kt + 3, kB, vB);
    }
#undef PREFETCH
#undef TILE_BODY

    // L: reduce over lg-groups, then across the 8 waves (disjoint m-block sets)
#pragma unroll
    for (int qblk = 0; qblk < 4; ++qblk) {
        Lacc[qblk] += __shfl_xor(Lacc[qblk], 16);
        Lacc[qblk] += __shfl_xor(Lacc[qblk], 32);
    }
    if (l < 16) {
#pragma unroll
        for (int qblk = 0; qblk < 4; ++qblk) cLs[w][qblk * 16 + lr] = Lacc[qblk];
    }
    __syncthreads();
    if (tid < 64) {
        float s = 0.f;
#pragma unroll
        for (int w2 = 0; w2 < 8; ++w2) s += cLs[w2][tid];
        cLt[tid] = 1.0f / s;
    }
    __syncthreads();

    const float g = gamma[0];
#pragma unroll
    for (int qblk = 0; qblk < 4; ++qblk) {
        float rI[4];
#pragma unroll
        for (int r = 0; r < 4; ++r) rI[r] = cLt[qblk * 16 + lg * 4 + r];
        const int nb = q0 + qblk * 16 + lg * 4;
#pragma unroll
        for (int ebi = 0; ebi < 2; ++ebi) {
            const int e = (w * 2 + ebi) * 16 + lr;
            const size_t idx = ((size_t)b * C_ + e) * N_ + nb;
            const f32x4 xv = *(const f32x4*)(x + idx);
            f32x4 ov;
#pragma unroll
            for (int r = 0; r < 4; ++r)
                ov[r] = g * acc[qblk][ebi][r] * rI[r] + xv[r];
            *(f32x4*)(out + idx) = ov;
        }
    }
}

extern "C" void kernel_launch(void* const* d_in, const int* in_sizes, int n_in,
                              void* d_out, int out_size, void* d_ws, size_t ws_size,
                              hipStream_t stream) {
    (void)in_sizes; (void)n_in; (void)out_size; (void)ws_size;
    const float* x     = (const float*)d_in[0];
    const float* y     = (const float*)d_in[1];
    const float* Wq    = (const float*)d_in[2];
    const float* bq    = (const float*)d_in[3];
    const float* Wk    = (const float*)d_in[4];
    const float* bk    = (const float*)d_in[5];
    const float* Wv    = (const float*)d_in[6];
    const float* bv    = (const float*)d_in[7];
    const float* gamma = (const float*)d_in[8];
    float* out = (float*)d_out;

    unsigned short* qf  = (unsigned short*)d_ws;
    unsigned short* kf  = qf + (size_t)B_ * N_ * CQK_;
    unsigned short* vf  = kf + (size_t)B_ * N_ * CQK_;
    unsigned short* Wqb = vf + (size_t)B_ * N_ * C_;
    unsigned short* Wkb = Wqb + CQK_ * C_;
    unsigned short* Wvb = Wkb + CQK_ * C_;

    unsigned short* xb = (unsigned short*)d_out;   // dead until attn epilogue
    unsigned short* yb = xb + (size_t)B_ * N_ * C_;

    transpose_kernel<<<dim3(576), 256, 0, stream>>>(x, y, Wq, Wk, Wv, xb, yb, Wqb, Wkb, Wvb);
    proj_gemm<<<dim3(256), 256, 0, stream>>>(xb, yb, Wqb, Wkb, Wvb, bq, bk, bv, qf, kf, vf);
    attn_kernel<<<dim3(256), 512, 0, stream>>>(qf, kf, vf, x, gamma, out);
}